// Round 16
// baseline (4160.626 us; speedup 1.0000x reference)
//
#include <hip/hip_runtime.h>

#define Bdim 64
#define Tdim 512
#define Fdim 512
#define Hdim 1024
#define NKB  48          // K-blocks of 32: 16 for x (K=512) + 32 for h (K=1024)
#define NXKB 16
#define NHKB 32
#define NWG  128
#define NTHR 512         // waves 0-3: h/gates (consumer), waves 4-7: zx producer

typedef __attribute__((ext_vector_type(8))) _Float16     f16x8;
typedef __attribute__((ext_vector_type(4))) float        f32x4;
typedef __attribute__((ext_vector_type(4))) unsigned int u32x4;

#define MFMA(a, b, c) __builtin_amdgcn_mfma_f32_16x16x32_f16((a), (b), (c), 0, 0, 0)

// ---- workspace layout (bytes) ----
// Wp    : fp16 fragment-linear weights, 12.6 MB
// bias_p: fp32[4096]
// hbuf  : fp16[4 slots][128 wg][64 row][8 col], 512 KB total (MALL-resident,
//         sentinel-tagged rotating buffer; read slot t%4, write (t+1)%4,
//         clear (t+2)%4)
#define WP_ELEMS    (256*48*64*8)
#define BIAS_OFF    ((size_t)WP_ELEMS * 2)
#define HBUF_OFF    (BIAS_OFF + 4096 * 4)
#define SLOT_BYTES  131072
#define SLOT_HALVES 65536

__device__ __forceinline__ float sigmoidf_(float v) {
    return 1.0f / (1.0f + __expf(-v));
}
__device__ __forceinline__ float tanhf_(float v) {
    return 1.0f - 2.0f / (1.0f + __expf(2.0f * v));
}

// MALL-coherent (L1/L2-bypass) 16B load / store: the poll IS the data load.
__device__ __forceinline__ f16x8 uload16(const void* p) {
    f16x8 r;
    asm volatile("global_load_dwordx4 %0, %1, off sc0 sc1"
                 : "=v"(r) : "v"(p) : "memory");
    return r;
}
__device__ __forceinline__ void ustore16(void* p, f32x4 v) {
    asm volatile("global_store_dwordx4 %0, %1, off sc0 sc1"
                 :: "v"(p), "v"(v) : "memory");
}

// Counted vmcnt wait (in-order retirement: upper bound, drain-safe) + sched fence
#define WAITV(N) do { asm volatile("s_waitcnt vmcnt(" #N ")" ::: "memory"); \
                      __builtin_amdgcn_sched_barrier(0); } while (0)

// sentinel = 0xFFFFFFFF per dword (fp16 -NaN pair; |h|<1 so never valid data)
__device__ __forceinline__ bool stale8(f16x8 v) {
    u32x4 u = __builtin_bit_cast(u32x4, v);
    return (u[0] == 0xFFFFFFFFu) | (u[1] == 0xFFFFFFFFu) |
           (u[2] == 0xFFFFFFFFu) | (u[3] == 0xFFFFFFFFu);
}

// LDS monotone token helpers (intra-WG producer/consumer handshake)
__device__ __forceinline__ unsigned ldtok(const unsigned* p) {
    return __hip_atomic_load(p, __ATOMIC_RELAXED, __HIP_MEMORY_SCOPE_WORKGROUP);
}
__device__ __forceinline__ void sttok(unsigned* p, unsigned v) {
    __hip_atomic_store(p, v, __ATOMIC_RELAXED, __HIP_MEMORY_SCOPE_WORKGROUP);
}

// Packed col Np = wg*32 + gate*8 + c  <->  orig col n = gate*1024 + wg*8 + c.
// Wp8[(tile*48 + kb)*64 + lane] = Wfull[kb*32 + (lane>>4)*8 + j][orig(tile*16 + (lane&15))]
__global__ void pack_w_kernel(const float* __restrict__ Wi, const float* __restrict__ Wh,
                              _Float16* __restrict__ Wp)
{
    int d = blockIdx.x * blockDim.x + threadIdx.x;   // 0 .. 786431
    int tn   = d / 3072;
    int r    = d % 3072;
    int kb   = r / 64;
    int lane = r % 64;
    int kg = lane >> 4, lm = lane & 15;
    int Np = tn * 16 + lm;
    int g    = Np >> 5;
    int lc   = Np & 31;
    int gate = lc >> 3, c = lc & 7;
    int n  = gate * Hdim + g * 8 + c;
    int k0 = kb * 32 + kg * 8;
    f16x8 v;
#pragma unroll
    for (int j = 0; j < 8; ++j) {
        int k = k0 + j;
        float w = (k < Fdim) ? Wi[(long)k * 4096 + n] : Wh[(long)(k - Fdim) * 4096 + n];
        v[j] = (_Float16)w;
    }
    ((f16x8*)Wp)[d] = v;
}

__global__ void pack_misc_kernel(const float* __restrict__ bh, const float* __restrict__ h0,
                                 float* __restrict__ bias_p, _Float16* __restrict__ hbuf)
{
    int t = blockIdx.x * blockDim.x + threadIdx.x;   // 0 .. 65535
    if (t < 4096) {
        int g = t >> 5, lc = t & 31;
        int gate = lc >> 3, c = lc & 7;
        bias_p[t] = bh[gate * Hdim + g * 8 + c];
    }
    {   // slot 0 = h(0), compact layout [wg][row][col]
        int wgp = t >> 9;
        int b   = (t >> 3) & 63;
        int c   = t & 7;
        hbuf[t] = (_Float16)h0[b * Hdim + wgp * 8 + c];
    }
    {   // slots 1..3 = sentinel (re-armed every launch; graph-replay safe)
        unsigned int* up = (unsigned int*)(hbuf + SLOT_HALVES);
        up[t] = 0xFFFFFFFFu;                          // slots 1,2 (65536 u32)
        if (t < 32768) up[65536 + t] = 0xFFFFFFFFu;   // slot 3
    }
}

__global__ __launch_bounds__(NTHR, 1)
void lstm_kernel(const float* __restrict__ x, const float* __restrict__ c0,
                 const f16x8* __restrict__ Wp8, const float* __restrict__ bias_p,
                 _Float16* __restrict__ hbuf, float* __restrict__ out)
{
    __shared__ f16x8 wlds[2 * NKB * 64];              // 96 KiB weight slice
    __shared__ float zlds[Bdim][33];                  // gates transpose staging
    __shared__ float zxlds[2][Bdim][33];              // zx double buffer
    __shared__ unsigned prodDone[4];                  // producer rt: zx(s) staged (value s+1)
    __shared__ unsigned consDone[4];                  // consumer rt: zx(s) consumed (value s+1)

    const int wg    = (blockIdx.x & 7) * 16 + (blockIdx.x >> 3);  // XCD-grouped
    const int tid   = threadIdx.x;
    const int wave  = tid >> 6;                       // 0..7
    const int lane  = tid & 63;
    const int kg    = lane >> 4;
    const int lm    = lane & 15;
    const bool isH  = (wave < 4);
    const int  rt   = isH ? wave : (wave - 4);        // row-tile 0..3 (16 rows each)

    // ---- stage the WG's weight slice into LDS once; init tokens ----
    {
        const f16x8* src = Wp8 + (size_t)wg * 2 * NKB * 64;
        for (int e = tid; e < 2 * NKB * 64; e += NTHR) wlds[e] = src[e];
    }
    if (tid < 4) { prodDone[tid] = 0; consDone[tid] = 0; }

    const float bias0 = bias_p[wg * 32 + lm];
    const float bias1 = bias_p[wg * 32 + 16 + lm];

    // gate ownership (h-waves): lane owns row grow = 16*wave + (l>>2), cols gjl, gjl+1
    const int grow = (wave & 3) * 16 + (lane >> 2);
    const int gjl  = (lane & 3) * 2;
    float cc0 = 0.f, cc1 = 0.f;
    if (isH) {
        cc0 = c0[grow * Hdim + wg * 8 + gjl];
        cc1 = c0[grow * Hdim + wg * 8 + gjl + 1];
    }

    const int arow = rt * 16 + lm;                    // MFMA A-operand row (batch)
    const float* __restrict__ xrow = x + (size_t)arow * Tdim * Fdim + kg * 8;

    char* __restrict__ hb  = (char*)hbuf;
    const char* __restrict__ hrd = hb + (size_t)kg * 1024 + (size_t)arow * 16;
    const size_t mypkt = (size_t)wg * 1024 + (size_t)grow * 16;

    // ---- x-producer phase: zx(TT) -> zxlds[BUF] (32 MFMAs, cols 0-31) ----
#define XPHASE(TT, BUF)                                                     \
    {                                                                       \
        const float* xt = xrow + (size_t)(TT) * Fdim;                       \
        f32x4 xa0 = {0.f, 0.f, 0.f, 0.f};                                   \
        f32x4 xa1 = {0.f, 0.f, 0.f, 0.f};                                   \
        _Pragma("unroll 8")                                                 \
        for (int kb = 0; kb < NXKB; ++kb) {                                 \
            const f32x4* ap = (const f32x4*)(xt + kb * 32);                 \
            f32x4 lo = ap[0];                                               \
            f32x4 hi = ap[1];                                               \
            f16x8 a;                                                        \
            _Pragma("unroll")                                               \
            for (int j = 0; j < 4; ++j) { a[j] = (_Float16)lo[j]; a[4+j] = (_Float16)hi[j]; } \
            xa0 = MFMA(a, wlds[kb * 64 + lane], xa0);                       \
            xa1 = MFMA(a, wlds[NKB * 64 + kb * 64 + lane], xa1);            \
        }                                                                   \
        int rbase = rt * 16 + kg * 4;                                       \
        _Pragma("unroll")                                                   \
        for (int r = 0; r < 4; ++r) {                                       \
            zxlds[BUF][rbase + r][lm]      = xa0[r];                        \
            zxlds[BUF][rbase + r][16 + lm] = xa1[r];                        \
        }                                                                   \
    }

    if (!isH) XPHASE(0, 0);                           // prologue: zx(0) staged
    __syncthreads();                                  // wlds + zx(0) + tokens visible
    if (!isH && lane == 0) sttok(&prodDone[rt], 1u);  // zx(0) ready

    for (int t = 0; t < Tdim; ++t) {
        if (isH) {
            // ================= CONSUMER =================
            // ---- pre-clear slot t+2 to sentinel (drained by this step's WAITV(0)
            //      before our own publish of h(t+2) next step) ----
            if (!(lane & 3)) {
                u32x4 sv = {0xFFFFFFFFu, 0xFFFFFFFFu, 0xFFFFFFFFu, 0xFFFFFFFFu};
                ustore16(hb + (size_t)((t + 2) & 3) * SLOT_BYTES + mypkt,
                         __builtin_bit_cast(f32x4, sv));
            }

            f32x4 acc0a = {bias0, bias0, bias0, bias0};
            f32x4 acc1a = {bias1, bias1, bias1, bias1};
            f32x4 acc0b = {0.f, 0.f, 0.f, 0.f};
            f32x4 acc1b = {0.f, 0.f, 0.f, 0.f};
            {
                const char* hq = hrd + (size_t)(t & 3) * SLOT_BYTES;
                f16x8 hA[8], hB[8], hC[8], hD[8];

#define HLOAD(BASE, H)                                                  \
                _Pragma("unroll")                                       \
                for (int k = 0; k < 8; ++k)                             \
                    H[k] = uload16(hq + (size_t)((BASE) + k) * 4096);

#define HCHECK(BASE, H)                                                 \
                {                                                       \
                    bool st[8]; bool any = false;                       \
                    _Pragma("unroll")                                   \
                    for (int k = 0; k < 8; ++k) { st[k] = stale8(H[k]); any |= st[k]; } \
                    while (__any(any)) {                                \
                        __builtin_amdgcn_s_sleep(1);                    \
                        _Pragma("unroll")                               \
                        for (int k = 0; k < 8; ++k)                     \
                            if (st[k]) H[k] = uload16(hq + (size_t)((BASE) + k) * 4096); \
                        WAITV(0);                                       \
                        any = false;                                    \
                        _Pragma("unroll")                               \
                        for (int k = 0; k < 8; ++k) { st[k] = stale8(H[k]); any |= st[k]; } \
                    }                                                   \
                }

#define HGROUP(BASE, H)                                                 \
                _Pragma("unroll")                                       \
                for (int k = 0; k < 8; ++k) {                           \
                    int kb = (BASE) + k;                                \
                    f16x8 bf0 = wlds[(NXKB + kb) * 64 + lane];          \
                    f16x8 bf1 = wlds[NKB * 64 + (NXKB + kb) * 64 + lane]; \
                    if (kb & 1) { acc0b = MFMA(H[k], bf0, acc0b); acc1b = MFMA(H[k], bf1, acc1b); } \
                    else        { acc0a = MFMA(H[k], bf0, acc0a); acc1a = MFMA(H[k], bf1, acc1a); } \
                }

                // All 32 loads issued at step start: the load is the rendezvous.
                // Older in queue: <=3 fire-and-forget (prev publish, prev out, clear).
                HLOAD(0,  hA);
                HLOAD(8,  hB);
                HLOAD(16, hC);
                HLOAD(24, hD);
                WAITV(24);                            // 3 older + g0 retired
                HCHECK(0,  hA);  HGROUP(0,  hA);
                WAITV(16);                            // g1 retired
                HCHECK(8,  hB);  HGROUP(8,  hB);
                WAITV(8);                             // g2 retired
                HCHECK(16, hC);  HGROUP(16, hC);
                WAITV(0);                             // g3 retired (also drains clear)
                HCHECK(24, hD);  HGROUP(24, hD);
#undef HLOAD
#undef HCHECK
#undef HGROUP
            }
            // ---- wait zx(t) staged, add it, stage z for gates, release buffer ----
            {
                while (ldtok(&prodDone[rt]) < (unsigned)(t + 1))
                    __builtin_amdgcn_s_sleep(1);
                const int buf = t & 1;
                int rbase = rt * 16 + kg * 4;
#pragma unroll
                for (int r = 0; r < 4; ++r) {
                    float z0 = acc0a[r] + acc0b[r] + zxlds[buf][rbase + r][lm];
                    float z1 = acc1a[r] + acc1b[r] + zxlds[buf][rbase + r][16 + lm];
                    zlds[rbase + r][lm]      = z0;
                    zlds[rbase + r][16 + lm] = z1;
                }
            }
            asm volatile("s_waitcnt lgkmcnt(0)" ::: "memory");
            __builtin_amdgcn_sched_barrier(0);
            if (lane == 0) sttok(&consDone[rt], (unsigned)(t + 1));   // zx(t) consumed

            // ---- gates: 2 cols per lane (rows wave-private in zlds) ----
            float hv0, hv1;
            {
                float i0 = sigmoidf_(zlds[grow][gjl]);
                float f0 = sigmoidf_(zlds[grow][8 + gjl]);
                float g0 = tanhf_(zlds[grow][16 + gjl]);
                float o0 = sigmoidf_(zlds[grow][24 + gjl]);
                cc0 = f0 * cc0 + i0 * g0;
                hv0 = o0 * tanhf_(cc0);

                float i1 = sigmoidf_(zlds[grow][gjl + 1]);
                float f1 = sigmoidf_(zlds[grow][8 + gjl + 1]);
                float g1 = tanhf_(zlds[grow][16 + gjl + 1]);
                float o1 = sigmoidf_(zlds[grow][24 + gjl + 1]);
                cc1 = f1 * cc1 + i1 * g1;
                hv1 = o1 * tanhf_(cc1);
            }

            // ---- publish h(t+1) into slot (t+1)&3: fire-and-forget, NO ack, NO flag ----
            {
                union { _Float16 h[2]; unsigned int u; } pk;
                pk.h[0] = (_Float16)hv0; pk.h[1] = (_Float16)hv1;
                const int lb = lane & ~3;
                unsigned int q0 = __shfl(pk.u, lb);
                unsigned int q1 = __shfl(pk.u, lb + 1);
                unsigned int q2 = __shfl(pk.u, lb + 2);
                unsigned int q3 = __shfl(pk.u, lb + 3);
                if (!(lane & 3)) {
                    u32x4 pkt = {q0, q1, q2, q3};
                    ustore16(hb + (size_t)((t + 1) & 3) * SLOT_BYTES + mypkt,
                             __builtin_bit_cast(f32x4, pkt));
                }
            }
            // out store (fire-and-forget; drained by next step's WAITV chain)
            {
                float2 ov; ov.x = hv0; ov.y = hv1;
                *(float2*)(out + ((size_t)grow * Tdim + t) * Hdim + wg * 8 + gjl) = ov;
            }
        } else {
            // ================= PRODUCER: zx(t+1) =================
            if (t) {
                while (ldtok(&consDone[rt]) < (unsigned)t)
                    __builtin_amdgcn_s_sleep(1);
            }
            {
                const int tn  = (t + 1 < Tdim) ? (t + 1) : t;
                const int buf = (t + 1) & 1;
                XPHASE(tn, buf);
            }
            asm volatile("s_waitcnt lgkmcnt(0)" ::: "memory");
            if (lane == 0) sttok(&prodDone[rt], (unsigned)(t + 2));   // zx(t+1) staged
        }
        // no per-step barrier: cross-WG sync via sentinel data; intra-WG via LDS tokens
    }
#undef XPHASE
}

extern "C" void kernel_launch(void* const* d_in, const int* in_sizes, int n_in,
                              void* d_out, int out_size, void* d_ws, size_t ws_size,
                              hipStream_t stream)
{
    const float* x  = (const float*)d_in[0];
    const float* c0 = (const float*)d_in[1];
    const float* h0 = (const float*)d_in[2];
    const float* Wi = (const float*)d_in[3];
    const float* Wh = (const float*)d_in[4];
    const float* bh = (const float*)d_in[5];
    float* out = (float*)d_out;

    char* ws = (char*)d_ws;
    _Float16* Wp     = (_Float16*)(ws);
    float*    bias_p = (float*)(ws + BIAS_OFF);
    _Float16* hbuf   = (_Float16*)(ws + HBUF_OFF);

    hipLaunchKernelGGL(pack_w_kernel,    dim3(3072), dim3(256), 0, stream, Wi, Wh, Wp);
    hipLaunchKernelGGL(pack_misc_kernel, dim3(256),  dim3(256), 0, stream, bh, h0, bias_p, hbuf);
    hipLaunchKernelGGL(lstm_kernel, dim3(NWG), dim3(NTHR), 0, stream,
                       x, c0, (const f16x8*)Wp, bias_p, hbuf, out);
}

// Round 17
// 3571.054 us; speedup vs baseline: 1.1651x; 1.1651x over previous
//
#include <hip/hip_runtime.h>

#define Bdim 64
#define Tdim 512
#define Fdim 512
#define Hdim 1024
#define NKB  48          // K-blocks of 32: 16 for x (K=512) + 32 for h (K=1024)
#define NXKB 16
#define NHKB 32
#define NWG  128
#define NTHR 512         // waves 0-3: h/gates (consumer), waves 4-7: zx producer; wave4 polls

typedef __attribute__((ext_vector_type(8))) _Float16     f16x8;
typedef __attribute__((ext_vector_type(4))) float        f32x4;
typedef __attribute__((ext_vector_type(4))) unsigned int u32x4;

#define MFMA(a, b, c) __builtin_amdgcn_mfma_f32_16x16x32_f16((a), (b), (c), 0, 0, 0)

// ---- workspace layout (bytes) — identical footprint to rounds 10-15 (~80 MB, proven) ----
#define WP_ELEMS    (256*48*64*8)
#define BIAS_OFF    ((size_t)WP_ELEMS * 2)
#define HBUF_OFF    (BIAS_OFF + 4096 * 4)
#define SLOT_BYTES  131072
#define NRING       513
#define FLAG_OFF    (HBUF_OFF + (size_t)NRING * SLOT_BYTES)
#define FLAG_STRIDE 32                               // uints (128 B) per flag

__device__ __forceinline__ float sigmoidf_(float v) {
    return 1.0f / (1.0f + __expf(-v));
}
__device__ __forceinline__ float tanhf_(float v) {
    return 1.0f - 2.0f / (1.0f + __expf(2.0f * v));
}

// L1-bypass, L2-cached 16B load (fast path: first reader per XCD fetches, rest hit L2)
__device__ __forceinline__ f16x8 uload16_l2(const void* p) {
    f16x8 r;
    asm volatile("global_load_dwordx4 %0, %1, off sc0"
                 : "=v"(r) : "v"(p) : "memory");
    return r;
}
// MALL-coherent bypass load (retry path only: never re-hit a sentinel-stale L2 line)
__device__ __forceinline__ f16x8 uload16_byp(const void* p) {
    f16x8 r;
    asm volatile("global_load_dwordx4 %0, %1, off sc0 sc1"
                 : "=v"(r) : "v"(p) : "memory");
    return r;
}
// Write-through to MALL (cross-XCD visible) 16B store.
__device__ __forceinline__ void ustore16(void* p, f32x4 v) {
    asm volatile("global_store_dwordx4 %0, %1, off sc0 sc1"
                 :: "v"(p), "v"(v) : "memory");
}

// Counted vmcnt wait (in-order retirement) + scheduling fence (rule #18)
#define WAITV(N) do { asm volatile("s_waitcnt vmcnt(" #N ")" ::: "memory"); \
                      __builtin_amdgcn_sched_barrier(0); } while (0)

// sentinel = 0xFFFFFFFF per dword (fp16 -NaN pair; |h|<1 so never valid data)
__device__ __forceinline__ bool stale8(f16x8 v) {
    u32x4 u = __builtin_bit_cast(u32x4, v);
    return (u[0] == 0xFFFFFFFFu) | (u[1] == 0xFFFFFFFFu) |
           (u[2] == 0xFFFFFFFFu) | (u[3] == 0xFFFFFFFFu);
}

// LDS monotone token helpers
__device__ __forceinline__ unsigned ldtok(const unsigned* p) {
    return __hip_atomic_load(p, __ATOMIC_RELAXED, __HIP_MEMORY_SCOPE_WORKGROUP);
}
__device__ __forceinline__ void sttok(unsigned* p, unsigned v) {
    __hip_atomic_store(p, v, __ATOMIC_RELAXED, __HIP_MEMORY_SCOPE_WORKGROUP);
}

// Packed col Np = wg*32 + gate*8 + c  <->  orig col n = gate*1024 + wg*8 + c.
// Wp8[(tile*48 + kb)*64 + lane] = Wfull[kb*32 + (lane>>4)*8 + j][orig(tile*16 + (lane&15))]
__global__ void pack_w_kernel(const float* __restrict__ Wi, const float* __restrict__ Wh,
                              _Float16* __restrict__ Wp)
{
    int d = blockIdx.x * blockDim.x + threadIdx.x;   // 0 .. 786431
    int tn   = d / 3072;
    int r    = d % 3072;
    int kb   = r / 64;
    int lane = r % 64;
    int kg = lane >> 4, lm = lane & 15;
    int Np = tn * 16 + lm;
    int g    = Np >> 5;
    int lc   = Np & 31;
    int gate = lc >> 3, c = lc & 7;
    int n  = gate * Hdim + g * 8 + c;
    int k0 = kb * 32 + kg * 8;
    f16x8 v;
#pragma unroll
    for (int j = 0; j < 8; ++j) {
        int k = k0 + j;
        float w = (k < Fdim) ? Wi[(long)k * 4096 + n] : Wh[(long)(k - Fdim) * 4096 + n];
        v[j] = (_Float16)w;
    }
    ((f16x8*)Wp)[d] = v;
}

// re-arm ring slots 1..512 to sentinel every launch (readers may race now)
__global__ void pack_ring_kernel(_Float16* __restrict__ hbuf)
{
    size_t i = (size_t)blockIdx.x * 256 + threadIdx.x;   // 0 .. 4194303 (16B each)
    u32x4 sv = {0xFFFFFFFFu, 0xFFFFFFFFu, 0xFFFFFFFFu, 0xFFFFFFFFu};
    *(u32x4*)((char*)hbuf + SLOT_BYTES + i * 16) = sv;
}

__global__ void pack_misc_kernel(const float* __restrict__ bh, const float* __restrict__ h0,
                                 float* __restrict__ bias_p, _Float16* __restrict__ hbuf,
                                 unsigned int* __restrict__ flags)
{
    int t = blockIdx.x * blockDim.x + threadIdx.x;   // 0 .. 65535
    if (t < NWG) flags[t * FLAG_STRIDE] = 0u;        // re-armed every launch
    if (t < 4096) {
        int g = t >> 5, lc = t & 31;
        int gate = lc >> 3, c = lc & 7;
        bias_p[t] = bh[gate * Hdim + g * 8 + c];
    }
    {   // ring slot 0 = h(0), compact layout [wg][row][col]
        int wgp = t >> 9;
        int b   = (t >> 3) & 63;
        int c   = t & 7;
        hbuf[t] = (_Float16)h0[b * Hdim + wgp * 8 + c];
    }
}

__global__ __launch_bounds__(NTHR, 1)
void lstm_kernel(const float* __restrict__ x, const float* __restrict__ c0,
                 const f16x8* __restrict__ Wp8, const float* __restrict__ bias_p,
                 _Float16* __restrict__ hbuf, unsigned int* __restrict__ flags,
                 float* __restrict__ out)
{
    __shared__ f16x8 wlds[2 * NKB * 64];              // 96 KiB weight slice
    __shared__ float zlds[Bdim][33];                  // gates transpose staging
    __shared__ float zxlds[2][Bdim][33];              // zx double buffer
    __shared__ unsigned gateT[4];                     // wave4: h(t) group-g flags observed
    __shared__ unsigned prodDone[4];                  // producer rt: zx(s) staged (value s+1)
    __shared__ unsigned consDone[4];                  // consumer rt: zx(s) consumed (value s+1)

    const int wg    = (blockIdx.x & 7) * 16 + (blockIdx.x >> 3);  // XCD-grouped
    const int tid   = threadIdx.x;
    const int wave  = tid >> 6;                       // 0..7
    const int lane  = tid & 63;
    const int kg    = lane >> 4;
    const int lm    = lane & 15;
    const bool isH  = (wave < 4);
    const int  rt   = isH ? wave : (wave - 4);        // row-tile 0..3 (16 rows each)

    // ---- stage the WG's weight slice into LDS once; init tokens ----
    {
        const f16x8* src = Wp8 + (size_t)wg * 2 * NKB * 64;
        for (int e = tid; e < 2 * NKB * 64; e += NTHR) wlds[e] = src[e];
    }
    if (tid < 4) { gateT[tid] = 0; prodDone[tid] = 0; consDone[tid] = 0; }

    const float bias0 = bias_p[wg * 32 + lm];
    const float bias1 = bias_p[wg * 32 + 16 + lm];

    // gate ownership (h-waves): lane owns row grow = 16*wave + (l>>2), cols gjl, gjl+1
    const int grow = (wave & 3) * 16 + (lane >> 2);
    const int gjl  = (lane & 3) * 2;
    float cc0 = 0.f, cc1 = 0.f;
    if (isH) {
        cc0 = c0[grow * Hdim + wg * 8 + gjl];
        cc1 = c0[grow * Hdim + wg * 8 + gjl + 1];
    }

    const int arow = rt * 16 + lm;                    // MFMA A-operand row (batch)
    const float* __restrict__ xrow = x + (size_t)arow * Tdim * Fdim + kg * 8;

    char* __restrict__ hb  = (char*)hbuf;
    const char* __restrict__ hrd = hb + (size_t)kg * 1024 + (size_t)arow * 16;
    const size_t mypkt = (size_t)wg * 1024 + (size_t)grow * 16;

    // ---- x-producer phase: zx(TT) -> zxlds[BUF] (32 MFMAs, cols 0-31) ----
#define XPHASE(TT, BUF)                                                     \
    {                                                                       \
        const float* xt = xrow + (size_t)(TT) * Fdim;                       \
        f32x4 xa0 = {0.f, 0.f, 0.f, 0.f};                                   \
        f32x4 xa1 = {0.f, 0.f, 0.f, 0.f};                                   \
        _Pragma("unroll 8")                                                 \
        for (int kb = 0; kb < NXKB; ++kb) {                                 \
            const f32x4* ap = (const f32x4*)(xt + kb * 32);                 \
            f32x4 lo = ap[0];                                               \
            f32x4 hi = ap[1];                                               \
            f16x8 a;                                                        \
            _Pragma("unroll")                                               \
            for (int j = 0; j < 4; ++j) { a[j] = (_Float16)lo[j]; a[4+j] = (_Float16)hi[j]; } \
            xa0 = MFMA(a, wlds[kb * 64 + lane], xa0);                       \
            xa1 = MFMA(a, wlds[NKB * 64 + kb * 64 + lane], xa1);            \
        }                                                                   \
        int rbase = rt * 16 + kg * 4;                                       \
        _Pragma("unroll")                                                   \
        for (int r = 0; r < 4; ++r) {                                       \
            zxlds[BUF][rbase + r][lm]      = xa0[r];                        \
            zxlds[BUF][rbase + r][16 + lm] = xa1[r];                        \
        }                                                                   \
    }

    if (!isH) XPHASE(0, 0);                           // prologue: zx(0) staged
    __syncthreads();                                  // wlds + zx(0) + tokens visible
    if (!isH && lane == 0) sttok(&prodDone[rt], 1u);  // zx(0) ready

    for (int t = 0; t < Tdim; ++t) {
        if (isH) {
            // ================= CONSUMER: h-MFMAs + gates + publish =================
            f32x4 acc0a = {bias0, bias0, bias0, bias0};
            f32x4 acc1a = {bias1, bias1, bias1, bias1};
            f32x4 acc0b = {0.f, 0.f, 0.f, 0.f};
            f32x4 acc1b = {0.f, 0.f, 0.f, 0.f};
            {
                const char* hq = hrd + (size_t)t * SLOT_BYTES;
                f16x8 hA[8], hB[8], hC[8], hD[8];

#define HGATE(G)                                                        \
                if (t) { while (ldtok(&gateT[G]) < (unsigned)t)         \
                             __builtin_amdgcn_s_sleep(1); }

#define HLOAD(BASE, H)                                                  \
                _Pragma("unroll")                                       \
                for (int k = 0; k < 8; ++k)                             \
                    H[k] = uload16_l2(hq + (size_t)((BASE) + k) * 4096);

// flag-beats-data fallback: retry stale packets with L2-bypass loads.
// Rare (packets issue before flag in the publisher wave + detect adds a RT).
#define HCHECK(BASE, H)                                                 \
                {                                                       \
                    bool st[8]; bool any = false;                       \
                    _Pragma("unroll")                                   \
                    for (int k = 0; k < 8; ++k) { st[k] = stale8(H[k]); any |= st[k]; } \
                    while (__any(any)) {                                \
                        _Pragma("unroll")                               \
                        for (int k = 0; k < 8; ++k)                     \
                            if (st[k]) H[k] = uload16_byp(hq + (size_t)((BASE) + k) * 4096); \
                        WAITV(0);                                       \
                        any = false;                                    \
                        _Pragma("unroll")                               \
                        for (int k = 0; k < 8; ++k) { st[k] = stale8(H[k]); any |= st[k]; } \
                    }                                                   \
                }

#define HGROUP(BASE, H)                                                 \
                _Pragma("unroll")                                       \
                for (int k = 0; k < 8; ++k) {                           \
                    int kb = (BASE) + k;                                \
                    f16x8 bf0 = wlds[(NXKB + kb) * 64 + lane];          \
                    f16x8 bf1 = wlds[NKB * 64 + (NXKB + kb) * 64 + lane]; \
                    if (kb & 1) { acc0b = MFMA(H[k], bf0, acc0b); acc1b = MFMA(H[k], bf1, acc1b); } \
                    else        { acc0a = MFMA(H[k], bf0, acc0a); acc1a = MFMA(H[k], bf1, acc1a); } \
                }

                // Group g covers wgs [32g, 32g+32); gated individually (stagger).
                // Older in queue: <=3 fire-and-forget from prev step (publish, flag, out).
                HGATE(0); HLOAD(0,  hA);
                HGATE(1); HLOAD(8,  hB);
                WAITV(8);                             // olders + g0 retired
                HCHECK(0,  hA);  HGROUP(0,  hA);
                HGATE(2); HLOAD(16, hC);
                WAITV(8);                             // g1 retired
                HCHECK(8,  hB);  HGROUP(8,  hB);
                HGATE(3); HLOAD(24, hD);
                WAITV(8);                             // g2 retired
                HCHECK(16, hC);  HGROUP(16, hC);
                WAITV(0);                             // g3 retired
                HCHECK(24, hD);  HGROUP(24, hD);
#undef HGATE
#undef HLOAD
#undef HCHECK
#undef HGROUP
            }
            // ---- wait zx(t) staged, add it, stage z for gates, release buffer ----
            {
                while (ldtok(&prodDone[rt]) < (unsigned)(t + 1))
                    __builtin_amdgcn_s_sleep(1);
                const int buf = t & 1;
                int rbase = rt * 16 + kg * 4;
#pragma unroll
                for (int r = 0; r < 4; ++r) {
                    float z0 = acc0a[r] + acc0b[r] + zxlds[buf][rbase + r][lm];
                    float z1 = acc1a[r] + acc1b[r] + zxlds[buf][rbase + r][16 + lm];
                    zlds[rbase + r][lm]      = z0;
                    zlds[rbase + r][16 + lm] = z1;
                }
            }
            asm volatile("s_waitcnt lgkmcnt(0)" ::: "memory");
            __builtin_amdgcn_sched_barrier(0);
            if (lane == 0) sttok(&consDone[rt], (unsigned)(t + 1));   // zx(t) consumed

            // ---- gates: 2 cols per lane (rows wave-private in zlds) ----
            float hv0, hv1;
            {
                float i0 = sigmoidf_(zlds[grow][gjl]);
                float f0 = sigmoidf_(zlds[grow][8 + gjl]);
                float g0 = tanhf_(zlds[grow][16 + gjl]);
                float o0 = sigmoidf_(zlds[grow][24 + gjl]);
                cc0 = f0 * cc0 + i0 * g0;
                hv0 = o0 * tanhf_(cc0);

                float i1 = sigmoidf_(zlds[grow][gjl + 1]);
                float f1 = sigmoidf_(zlds[grow][8 + gjl + 1]);
                float g1 = tanhf_(zlds[grow][16 + gjl + 1]);
                float o1 = sigmoidf_(zlds[grow][24 + gjl + 1]);
                cc1 = f1 * cc1 + i1 * g1;
                hv1 = o1 * tanhf_(cc1);
            }

            // ---- publish h(t+1) into ring slot t+1: fire-and-forget, NO ack.
            //      Flag posted immediately; readers' sentinel check covers the
            //      flag-beats-data window. ----
            {
                union { _Float16 h[2]; unsigned int u; } pk;
                pk.h[0] = (_Float16)hv0; pk.h[1] = (_Float16)hv1;
                const int lb = lane & ~3;
                unsigned int q0 = __shfl(pk.u, lb);
                unsigned int q1 = __shfl(pk.u, lb + 1);
                unsigned int q2 = __shfl(pk.u, lb + 2);
                unsigned int q3 = __shfl(pk.u, lb + 3);
                if (!(lane & 3)) {
                    u32x4 pkt = {q0, q1, q2, q3};
                    ustore16(hb + (size_t)(t + 1) * SLOT_BYTES + mypkt,
                             __builtin_bit_cast(f32x4, pkt));
                }
            }
            if (lane == 0)
                __hip_atomic_fetch_add(flags + (size_t)wg * FLAG_STRIDE, 1u,
                                       __ATOMIC_RELAXED, __HIP_MEMORY_SCOPE_AGENT);
            // out store (fire-and-forget; drained by next step's counted waits)
            {
                float2 ov; ov.x = hv0; ov.y = hv1;
                *(float2*)(out + ((size_t)grow * Tdim + t) * Hdim + wg * 8 + gjl) = ov;
            }
        } else {
            // ================= PRODUCER: zx(t+1); wave4 also polls+posts gates =================
            {
                if (t) {
                    while (ldtok(&consDone[rt]) < (unsigned)t)
                        __builtin_amdgcn_s_sleep(1);
                }
                const int tn  = (t + 1 < Tdim) ? (t + 1) : t;
                const int buf = (t + 1) & 1;
                XPHASE(tn, buf);
            }
            asm volatile("s_waitcnt lgkmcnt(0)" ::: "memory");
            if (lane == 0) sttok(&prodDone[rt], (unsigned)(t + 2));   // zx(t+1) staged

            if (wave == 4 && t + 1 < Tdim) {
                const unsigned tgt = 4u * (unsigned)(t + 1);
                unsigned posted = 0;
                while (posted != 0xFu) {
                    unsigned f0 = __hip_atomic_load(flags + (size_t)lane * FLAG_STRIDE,
                                                    __ATOMIC_RELAXED, __HIP_MEMORY_SCOPE_AGENT);
                    unsigned f1 = __hip_atomic_load(flags + (size_t)(64 + lane) * FLAG_STRIDE,
                                                    __ATOMIC_RELAXED, __HIP_MEMORY_SCOPE_AGENT);
                    unsigned long long b0 = __ballot(f0 >= tgt);
                    unsigned long long b1 = __ballot(f1 >= tgt);
                    if (!(posted & 1u) && (unsigned)b0 == 0xFFFFFFFFu) {
                        if (lane == 0) sttok(&gateT[0], (unsigned)(t + 1));
                        posted |= 1u;
                    }
                    if (!(posted & 2u) && (unsigned)(b0 >> 32) == 0xFFFFFFFFu) {
                        if (lane == 0) sttok(&gateT[1], (unsigned)(t + 1));
                        posted |= 2u;
                    }
                    if (!(posted & 4u) && (unsigned)b1 == 0xFFFFFFFFu) {
                        if (lane == 0) sttok(&gateT[2], (unsigned)(t + 1));
                        posted |= 4u;
                    }
                    if (!(posted & 8u) && (unsigned)(b1 >> 32) == 0xFFFFFFFFu) {
                        if (lane == 0) sttok(&gateT[3], (unsigned)(t + 1));
                        posted |= 8u;
                    }
                    if (posted != 0xFu) __builtin_amdgcn_s_sleep(1);
                }
            }
        }
        // no per-step barrier: cross-WG deps via flags+sentinel; intra-WG via LDS tokens
    }
#undef XPHASE
}

extern "C" void kernel_launch(void* const* d_in, const int* in_sizes, int n_in,
                              void* d_out, int out_size, void* d_ws, size_t ws_size,
                              hipStream_t stream)
{
    const float* x  = (const float*)d_in[0];
    const float* c0 = (const float*)d_in[1];
    const float* h0 = (const float*)d_in[2];
    const float* Wi = (const float*)d_in[3];
    const float* Wh = (const float*)d_in[4];
    const float* bh = (const float*)d_in[5];
    float* out = (float*)d_out;

    char* ws = (char*)d_ws;
    _Float16*     Wp     = (_Float16*)(ws);
    float*        bias_p = (float*)(ws + BIAS_OFF);
    _Float16*     hbuf   = (_Float16*)(ws + HBUF_OFF);
    unsigned int* flags  = (unsigned int*)(ws + FLAG_OFF);

    hipLaunchKernelGGL(pack_w_kernel,    dim3(3072),  dim3(256), 0, stream, Wi, Wh, Wp);
    hipLaunchKernelGGL(pack_ring_kernel, dim3(16384), dim3(256), 0, stream, hbuf);
    hipLaunchKernelGGL(pack_misc_kernel, dim3(256),   dim3(256), 0, stream, bh, h0, bias_p, hbuf, flags);
    hipLaunchKernelGGL(lstm_kernel, dim3(NWG), dim3(NTHR), 0, stream,
                       x, c0, (const f16x8*)Wp, bias_p, hbuf, flags, out);
}

// Round 18
// 3147.098 us; speedup vs baseline: 1.3221x; 1.1347x over previous
//
#include <hip/hip_runtime.h>

#define Bdim 64
#define Tdim 512
#define Fdim 512
#define Hdim 1024
#define NKB  48          // K-blocks of 32: 16 for x (K=512) + 32 for h (K=1024)
#define NXKB 16
#define NHKB 32
#define NWG  128
#define NTHR 512         // waves 0-3: h/gates (consumer), waves 4-7: zx producer; wave4 also polls

typedef __attribute__((ext_vector_type(8))) _Float16     f16x8;
typedef __attribute__((ext_vector_type(4))) float        f32x4;
typedef __attribute__((ext_vector_type(4))) unsigned int u32x4;

#define MFMA(a, b, c) __builtin_amdgcn_mfma_f32_16x16x32_f16((a), (b), (c), 0, 0, 0)

// ---- workspace layout (bytes) — identical footprint to rounds 10-14 (~80 MB, proven) ----
#define WP_ELEMS    (256*48*64*8)
#define BIAS_OFF    ((size_t)WP_ELEMS * 2)
#define HBUF_OFF    (BIAS_OFF + 4096 * 4)
#define SLOT_BYTES  131072
#define NRING       513
#define FLAG_OFF    (HBUF_OFF + (size_t)NRING * SLOT_BYTES)
#define FLAG_STRIDE 32                               // uints (128 B) per flag

__device__ __forceinline__ float sigmoidf_(float v) {
    return 1.0f / (1.0f + __expf(-v));
}
__device__ __forceinline__ float tanhf_(float v) {
    return 1.0f - 2.0f / (1.0f + __expf(2.0f * v));
}

// L1-bypass, L2-cached 16B load (h ring: first reader per XCD fetches, rest hit L2)
__device__ __forceinline__ f16x8 uload16_l2(const void* p) {
    f16x8 r;
    asm volatile("global_load_dwordx4 %0, %1, off sc0"
                 : "=v"(r) : "v"(p) : "memory");
    return r;
}
// Write-through to MALL (cross-XCD visible) 16B store.
__device__ __forceinline__ void ustore16(void* p, f32x4 v) {
    asm volatile("global_store_dwordx4 %0, %1, off sc0 sc1"
                 :: "v"(p), "v"(v) : "memory");
}

// Counted vmcnt wait (in-order retirement) + scheduling fence (rule #18)
#define WAITV(N) do { asm volatile("s_waitcnt vmcnt(" #N ")" ::: "memory"); \
                      __builtin_amdgcn_sched_barrier(0); } while (0)

// LDS monotone token helpers (workgroup scope => ds ops, re-read every poll)
__device__ __forceinline__ unsigned ldtok(const unsigned* p) {
    return __hip_atomic_load(p, __ATOMIC_RELAXED, __HIP_MEMORY_SCOPE_WORKGROUP);
}
__device__ __forceinline__ void sttok(unsigned* p, unsigned v) {
    __hip_atomic_store(p, v, __ATOMIC_RELAXED, __HIP_MEMORY_SCOPE_WORKGROUP);
}

// Packed col Np = wg*32 + gate*8 + c  <->  orig col n = gate*1024 + wg*8 + c.
// Wp8[(tile*48 + kb)*64 + lane] = Wfull[kb*32 + (lane>>4)*8 + j][orig(tile*16 + (lane&15))]
__global__ void pack_w_kernel(const float* __restrict__ Wi, const float* __restrict__ Wh,
                              _Float16* __restrict__ Wp)
{
    int d = blockIdx.x * blockDim.x + threadIdx.x;   // 0 .. 786431
    int tn   = d / 3072;
    int r    = d % 3072;
    int kb   = r / 64;
    int lane = r % 64;
    int kg = lane >> 4, lm = lane & 15;
    int Np = tn * 16 + lm;
    int g    = Np >> 5;
    int lc   = Np & 31;
    int gate = lc >> 3, c = lc & 7;
    int n  = gate * Hdim + g * 8 + c;
    int k0 = kb * 32 + kg * 8;
    f16x8 v;
#pragma unroll
    for (int j = 0; j < 8; ++j) {
        int k = k0 + j;
        float w = (k < Fdim) ? Wi[(long)k * 4096 + n] : Wh[(long)(k - Fdim) * 4096 + n];
        v[j] = (_Float16)w;
    }
    ((f16x8*)Wp)[d] = v;
}

__global__ void pack_misc_kernel(const float* __restrict__ bh, const float* __restrict__ h0,
                                 float* __restrict__ bias_p, _Float16* __restrict__ hbuf,
                                 unsigned int* __restrict__ flags)
{
    int t = blockIdx.x * blockDim.x + threadIdx.x;   // 0 .. 65535
    if (t < NWG) flags[t * FLAG_STRIDE] = 0u;        // re-armed every launch
    if (t < 4096) {
        int g = t >> 5, lc = t & 31;
        int gate = lc >> 3, c = lc & 7;
        bias_p[t] = bh[gate * Hdim + g * 8 + c];
    }
    {   // ring slot 0 = h(0), compact layout [wg][row][col]
        int wgp = t >> 9;
        int b   = (t >> 3) & 63;
        int c   = t & 7;
        hbuf[t] = (_Float16)h0[b * Hdim + wgp * 8 + c];
    }
}

__global__ __launch_bounds__(NTHR, 1)
void lstm_kernel(const float* __restrict__ x, const float* __restrict__ c0,
                 const f16x8* __restrict__ Wp8, const float* __restrict__ bias_p,
                 _Float16* __restrict__ hbuf, unsigned int* __restrict__ flags,
                 float* __restrict__ out)
{
    __shared__ f16x8 wlds[2 * NKB * 64];              // 96 KiB weight slice
    __shared__ float zlds[Bdim][33];                  // gates transpose staging (wave-private rows)
    __shared__ float zxlds[2][Bdim][33];              // zx double buffer (producer->consumer)
    __shared__ unsigned gateT[4];                     // wave4: h(t) group-g flags observed (value t)
    __shared__ unsigned prodDone[4];                  // producer rt: zx(s) staged (value s+1)
    __shared__ unsigned consDone[4];                  // consumer rt: zx(s) consumed (value s+1)

    const int wg    = (blockIdx.x & 7) * 16 + (blockIdx.x >> 3);  // XCD-grouped
    const int tid   = threadIdx.x;
    const int wave  = tid >> 6;                       // 0..7
    const int lane  = tid & 63;
    const int kg    = lane >> 4;
    const int lm    = lane & 15;
    const bool isH  = (wave < 4);
    const int  rt   = isH ? wave : (wave - 4);        // row-tile 0..3 (16 rows each)

    // ---- stage the WG's weight slice into LDS once; init tokens ----
    {
        const f16x8* src = Wp8 + (size_t)wg * 2 * NKB * 64;
        for (int e = tid; e < 2 * NKB * 64; e += NTHR) wlds[e] = src[e];
    }
    if (tid < 4) { gateT[tid] = 0; prodDone[tid] = 0; consDone[tid] = 0; }

    const float bias0 = bias_p[wg * 32 + lm];
    const float bias1 = bias_p[wg * 32 + 16 + lm];

    // gate ownership (h-waves): lane owns row grow = 16*wave + (l>>2), cols gjl, gjl+1
    const int grow = (wave & 3) * 16 + (lane >> 2);
    const int gjl  = (lane & 3) * 2;
    float cc0 = 0.f, cc1 = 0.f;
    if (isH) {
        cc0 = c0[grow * Hdim + wg * 8 + gjl];
        cc1 = c0[grow * Hdim + wg * 8 + gjl + 1];
    }

    const int arow = rt * 16 + lm;                    // MFMA A-operand row (batch)
    const float* __restrict__ xrow = x + (size_t)arow * Tdim * Fdim + kg * 8;

    char* __restrict__ hb  = (char*)hbuf;
    const char* __restrict__ hrd = hb + (size_t)kg * 1024 + (size_t)arow * 16;
    const size_t mypkt = (size_t)wg * 1024 + (size_t)grow * 16;

    // ---- x-producer phase: zx(TT) -> zxlds[BUF] (32 MFMAs, cols 0-31) ----
#define XPHASE(TT, BUF)                                                     \
    {                                                                       \
        const float* xt = xrow + (size_t)(TT) * Fdim;                       \
        f32x4 xa0 = {0.f, 0.f, 0.f, 0.f};                                   \
        f32x4 xa1 = {0.f, 0.f, 0.f, 0.f};                                   \
        _Pragma("unroll 8")                                                 \
        for (int kb = 0; kb < NXKB; ++kb) {                                 \
            const f32x4* ap = (const f32x4*)(xt + kb * 32);                 \
            f32x4 lo = ap[0];                                               \
            f32x4 hi = ap[1];                                               \
            f16x8 a;                                                        \
            _Pragma("unroll")                                               \
            for (int j = 0; j < 4; ++j) { a[j] = (_Float16)lo[j]; a[4+j] = (_Float16)hi[j]; } \
            xa0 = MFMA(a, wlds[kb * 64 + lane], xa0);                       \
            xa1 = MFMA(a, wlds[NKB * 64 + kb * 64 + lane], xa1);            \
        }                                                                   \
        int rbase = rt * 16 + kg * 4;                                       \
        _Pragma("unroll")                                                   \
        for (int r = 0; r < 4; ++r) {                                       \
            zxlds[BUF][rbase + r][lm]      = xa0[r];                        \
            zxlds[BUF][rbase + r][16 + lm] = xa1[r];                        \
        }                                                                   \
    }

    if (!isH) XPHASE(0, 0);                           // prologue: zx(0) staged
    __syncthreads();                                  // wlds + zx(0) + tokens visible
    if (!isH && lane == 0) sttok(&prodDone[rt], 1u);  // zx(0) ready

    for (int t = 0; t < Tdim; ++t) {
        if (isH) {
            // ================= CONSUMER: h-MFMAs + gates + publish =================
            f32x4 acc0a = {bias0, bias0, bias0, bias0};
            f32x4 acc1a = {bias1, bias1, bias1, bias1};
            f32x4 acc0b = {0.f, 0.f, 0.f, 0.f};
            f32x4 acc1b = {0.f, 0.f, 0.f, 0.f};
            {
                const char* hq = hrd + (size_t)t * SLOT_BYTES;
                f16x8 hA[8], hB[8], hC[8], hD[8];

#define HGATE(G)                                                        \
                if (t) { while (ldtok(&gateT[G]) < (unsigned)t)         \
                             __builtin_amdgcn_s_sleep(1); }

#define HLOAD(BASE, H)                                                  \
                _Pragma("unroll")                                       \
                for (int k = 0; k < 8; ++k)                             \
                    H[k] = uload16_l2(hq + (size_t)((BASE) + k) * 4096);

#define HGROUP(BASE, H)                                                 \
                _Pragma("unroll")                                       \
                for (int k = 0; k < 8; ++k) {                           \
                    int kb = (BASE) + k;                                \
                    f16x8 bf0 = wlds[(NXKB + kb) * 64 + lane];          \
                    f16x8 bf1 = wlds[NKB * 64 + (NXKB + kb) * 64 + lane]; \
                    if (kb & 1) { acc0b = MFMA(H[k], bf0, acc0b); acc1b = MFMA(H[k], bf1, acc1b); } \
                    else        { acc0a = MFMA(H[k], bf0, acc0a); acc1a = MFMA(H[k], bf1, acc1a); } \
                }

                // Group g reads packets of wgs [32g, 32g+32): gate each group
                // individually; loads issue as soon as that subset published.
                // vmcnt entering: 2 older fire-and-forget instrs (flag atomic, out).
                HGATE(0); HLOAD(0,  hA);              // 10 outstanding
                HGATE(1); HLOAD(8,  hB);              // 18
                WAITV(8);                             // 2 old + g0 retired
                HGROUP(0,  hA);
                HGATE(2); HLOAD(16, hC);              // 16
                WAITV(8);                             // g1 retired
                HGROUP(8,  hB);
                HGATE(3); HLOAD(24, hD);              // 16
                WAITV(8);                             // g2 retired
                HGROUP(16, hC);
                WAITV(0);                             // g3 retired
                HGROUP(24, hD);
#undef HGATE
#undef HLOAD
#undef HGROUP
            }
            // ---- wait zx(t) staged, add it, stage z for gates, release buffer ----
            {
                while (ldtok(&prodDone[rt]) < (unsigned)(t + 1))
                    __builtin_amdgcn_s_sleep(1);
                const int buf = t & 1;
                int rbase = rt * 16 + kg * 4;
#pragma unroll
                for (int r = 0; r < 4; ++r) {
                    float z0 = acc0a[r] + acc0b[r] + zxlds[buf][rbase + r][lm];
                    float z1 = acc1a[r] + acc1b[r] + zxlds[buf][rbase + r][16 + lm];
                    zlds[rbase + r][lm]      = z0;
                    zlds[rbase + r][16 + lm] = z1;
                }
            }
            asm volatile("s_waitcnt lgkmcnt(0)" ::: "memory");
            __builtin_amdgcn_sched_barrier(0);
            if (lane == 0) sttok(&consDone[rt], (unsigned)(t + 1));   // zx(t) consumed

            // ---- gates: 2 cols per lane (rows wave-private in zlds) ----
            float hv0, hv1;
            {
                float i0 = sigmoidf_(zlds[grow][gjl]);
                float f0 = sigmoidf_(zlds[grow][8 + gjl]);
                float g0 = tanhf_(zlds[grow][16 + gjl]);
                float o0 = sigmoidf_(zlds[grow][24 + gjl]);
                cc0 = f0 * cc0 + i0 * g0;
                hv0 = o0 * tanhf_(cc0);

                float i1 = sigmoidf_(zlds[grow][gjl + 1]);
                float f1 = sigmoidf_(zlds[grow][8 + gjl + 1]);
                float g1 = tanhf_(zlds[grow][16 + gjl + 1]);
                float o1 = sigmoidf_(zlds[grow][24 + gjl + 1]);
                cc1 = f1 * cc1 + i1 * g1;
                hv1 = o1 * tanhf_(cc1);
            }

            // ---- publish h(t+1) into ring slot t+1: 4-lane gather -> one 16B store ----
            {
                union { _Float16 h[2]; unsigned int u; } pk;
                pk.h[0] = (_Float16)hv0; pk.h[1] = (_Float16)hv1;
                const int lb = lane & ~3;
                unsigned int q0 = __shfl(pk.u, lb);
                unsigned int q1 = __shfl(pk.u, lb + 1);
                unsigned int q2 = __shfl(pk.u, lb + 2);
                unsigned int q3 = __shfl(pk.u, lb + 3);
                if (!(lane & 3)) {
                    u32x4 pkt = {q0, q1, q2, q3};
                    ustore16(hb + (size_t)(t + 1) * SLOT_BYTES + mypkt,
                             __builtin_bit_cast(f32x4, pkt));
                }
            }
            WAITV(0);                                 // publish acked at MALL
            if (lane == 0)
                __hip_atomic_fetch_add(flags + (size_t)wg * FLAG_STRIDE, 1u,
                                       __ATOMIC_RELAXED, __HIP_MEMORY_SCOPE_AGENT);
            // out store (fire-and-forget; one of the "2 older" next step)
            {
                float2 ov; ov.x = hv0; ov.y = hv1;
                *(float2*)(out + ((size_t)grow * Tdim + t) * Hdim + wg * 8 + gjl) = ov;
            }
        } else {
            // ================= PRODUCER: zx(t+1); wave4 also polls+posts gates =================
            {
                // don't overwrite buf (t+1)&1 until its previous contents (zx(t-1)) consumed
                if (t) {
                    while (ldtok(&consDone[rt]) < (unsigned)t)
                        __builtin_amdgcn_s_sleep(1);
                }
                const int tn  = (t + 1 < Tdim) ? (t + 1) : t;
                const int buf = (t + 1) & 1;
                XPHASE(tn, buf);
            }
            asm volatile("s_waitcnt lgkmcnt(0)" ::: "memory");
            if (lane == 0) sttok(&prodDone[rt], (unsigned)(t + 2));   // zx(t+1) staged

            if (wave == 4 && t + 1 < Tdim) {
                // poll the 128 flags for generation t+1; post per-group tokens as
                // each 32-flag subset completes (group g = wgs [32g, 32g+32))
                const unsigned tgt = 4u * (unsigned)(t + 1);
                unsigned posted = 0;
                while (posted != 0xFu) {
                    unsigned f0 = __hip_atomic_load(flags + (size_t)lane * FLAG_STRIDE,
                                                    __ATOMIC_RELAXED, __HIP_MEMORY_SCOPE_AGENT);
                    unsigned f1 = __hip_atomic_load(flags + (size_t)(64 + lane) * FLAG_STRIDE,
                                                    __ATOMIC_RELAXED, __HIP_MEMORY_SCOPE_AGENT);
                    unsigned long long b0 = __ballot(f0 >= tgt);
                    unsigned long long b1 = __ballot(f1 >= tgt);
                    if (!(posted & 1u) && (unsigned)b0 == 0xFFFFFFFFu) {
                        if (lane == 0) sttok(&gateT[0], (unsigned)(t + 1));
                        posted |= 1u;
                    }
                    if (!(posted & 2u) && (unsigned)(b0 >> 32) == 0xFFFFFFFFu) {
                        if (lane == 0) sttok(&gateT[1], (unsigned)(t + 1));
                        posted |= 2u;
                    }
                    if (!(posted & 4u) && (unsigned)b1 == 0xFFFFFFFFu) {
                        if (lane == 0) sttok(&gateT[2], (unsigned)(t + 1));
                        posted |= 4u;
                    }
                    if (!(posted & 8u) && (unsigned)(b1 >> 32) == 0xFFFFFFFFu) {
                        if (lane == 0) sttok(&gateT[3], (unsigned)(t + 1));
                        posted |= 8u;
                    }
                    if (posted != 0xFu) __builtin_amdgcn_s_sleep(1);
                }
            }
        }
        // no per-step barrier: all cross-wave deps carried by monotone LDS tokens
    }
#undef XPHASE
}

extern "C" void kernel_launch(void* const* d_in, const int* in_sizes, int n_in,
                              void* d_out, int out_size, void* d_ws, size_t ws_size,
                              hipStream_t stream)
{
    const float* x  = (const float*)d_in[0];
    const float* c0 = (const float*)d_in[1];
    const float* h0 = (const float*)d_in[2];
    const float* Wi = (const float*)d_in[3];
    const float* Wh = (const float*)d_in[4];
    const float* bh = (const float*)d_in[5];
    float* out = (float*)d_out;

    char* ws = (char*)d_ws;
    _Float16*     Wp     = (_Float16*)(ws);
    float*        bias_p = (float*)(ws + BIAS_OFF);
    _Float16*     hbuf   = (_Float16*)(ws + HBUF_OFF);
    unsigned int* flags  = (unsigned int*)(ws + FLAG_OFF);

    hipLaunchKernelGGL(pack_w_kernel,    dim3(3072), dim3(256), 0, stream, Wi, Wh, Wp);
    hipLaunchKernelGGL(pack_misc_kernel, dim3(256),  dim3(256), 0, stream, bh, h0, bias_p, hbuf, flags);
    hipLaunchKernelGGL(lstm_kernel, dim3(NWG), dim3(NTHR), 0, stream,
                       x, c0, (const f16x8*)Wp, bias_p, hbuf, flags, out);
}